// Round 7
// baseline (331.289 us; speedup 1.0000x reference)
//
#include <hip/hip_runtime.h>

#define NPTS   8192
#define CCH    32
#define LDIM   64
#define ODIM   128
#define KNN    16
#define QPB    64                  // queries per block (16 per wave = MFMA tile rows)
#define TILEC  64                  // candidates per LDS tile (4 groups scan in parallel)
#define NTIL   (NPTS / TILEC)      // 128
#define NBLK   ((4 * NPTS) / QPB)  // 512 blocks
#define SCAP   57                  // survivor capacity (worst ~40); odd stride -> conflict-free rank reads
#define MARGIN 0.75f               // >= 2*eps bound for fp16 distance error
#define T32STR 129                 // t32 row stride (odd -> conflict-free column reads)

typedef _Float16 half8   __attribute__((ext_vector_type(8)));
typedef float    float4v __attribute__((ext_vector_type(4)));

// 1024-thread block = 16 waves = 4 scan groups of 4 waves. Group g scans tiles
// with (tile&3)==g (32 tiles of 64 cands each) with its own double-buffer pair.
// Same total work as the 8-wave version, but 2 blocks/CU x 16 waves = 32
// waves/CU = 8 waves/SIMD (FULL) vs 4 before  -- R6 evidence: occupancy 42%,
// VALUBusy 48%, all rooflines <2% => latency-bound with empty wave slots;
// grid was capped at 2 blocks/CU x 8 waves. VGPR must stay <= 64 (8 waves/SIMD
// rung, R3-R6 evidence); scan loop shrinks (4 st/iter), unroll limits kept.
//
// Threshold refinement: 64 partitions (16 cols x 4 groups) x top-2 = 128
// values/query; refined-partition union contains the coarse union's top-2s =>
// 16th smallest can only DECREASE => survivors shrink => SCAP analysis holds.
//
// LDS map:
//  scan:   buf[g][p] @ (g*2+p)*4352, 8 x 4352 = 34816  (4096 xh + 256 sq each)
//          slist @34816 (64*57*4 = 14592) | scnt @49408 (256) | tq @49664 (256)
//          kn @49920 (4096)  -> total 54016 (2 blocks/CU: wave-slot capped)
//          t32 overlay @0 (64*129*4 = 33024) after pass-1 (dead before pass-2 staging)
//  pass3:  skeys overlay @0 (14592)   (stage bufs dead)
//  epilog: pl @0 (8448) | hh @8704 (16640)   (kn alive @49920)
#define LDS_BYTES 54016
#define OFF_SQ   4096              // sq row offset inside a stage buffer
#define OFF_SL   34816
#define OFF_SC   49408
#define OFF_TQ   49664
#define OFF_KN   49920
#define OFF_HH   8704

__device__ __forceinline__ void gload_lds16(const void* g, void* l) {
    __builtin_amdgcn_global_load_lds(
        (const __attribute__((address_space(1))) unsigned int*)g,
        (__attribute__((address_space(3))) unsigned int*)l, 16, 0, 0);
}
__device__ __forceinline__ void gload_lds4(const void* g, void* l) {
    __builtin_amdgcn_global_load_lds(
        (const __attribute__((address_space(1))) unsigned int*)g,
        (__attribute__((address_space(3))) unsigned int*)l, 4, 0, 0);
}

// Prologue: squared norms (same summation order -> identical bits) and fp16
// candidates written ONCE in B-fragment order for TILEC=64 tiles:
//   point p, channel c=q*8+j -> half8 index (p>>6)*256 + ((p>>4)&3)*64 + (p&15), quad q stride 16
// i.e. [tile64][st(4)][quad][col][8ch]; global_load_lds stages linearly and the
// wave's ds_read_b128 at (st*1024 + lane*16) is the canonical conflict-free pattern.
__global__ void prep_kernel(const float* __restrict__ x, float* __restrict__ sqg,
                            _Float16* __restrict__ xh) {
    int p = blockIdx.x * 256 + threadIdx.x;      // 0..32767
    const float4* src = (const float4*)(x + (size_t)p * CCH);
    float4 f[8];
    #pragma unroll
    for (int k = 0; k < 8; ++k) f[k] = src[k];
    float s = 0.f;
    #pragma unroll
    for (int k = 0; k < 8; ++k)
        s += f[k].x * f[k].x + f[k].y * f[k].y + f[k].z * f[k].z + f[k].w * f[k].w;
    sqg[p] = s;
    half8* dst = (half8*)xh + ((p >> 6) * 256 + ((p >> 4) & 3) * 64 + (p & 15));
    #pragma unroll
    for (int q = 0; q < 4; ++q) {
        float4 a = f[2 * q], c = f[2 * q + 1];
        half8 h;
        h[0] = (_Float16)a.x; h[1] = (_Float16)a.y; h[2] = (_Float16)a.z; h[3] = (_Float16)a.w;
        h[4] = (_Float16)c.x; h[5] = (_Float16)c.y; h[6] = (_Float16)c.z; h[7] = (_Float16)c.w;
        dst[q * 16] = h;                          // quad stride = 64 halfs = 16 half8
    }
}

__global__ __launch_bounds__(1024, 2)
void graph_layer_kernel(const float* __restrict__ x,
                        const float* __restrict__ sqg,
                        const _Float16* __restrict__ xh,
                        const float* __restrict__ Wl,
                        const float* __restrict__ bl,
                        const float* __restrict__ Wc,
                        const float* __restrict__ bc,
                        float* __restrict__ out)
{
    __shared__ __align__(16) char smem[LDS_BYTES];
    int*   slist = (int*)(smem + OFF_SL);
    float* t32   = (float*)smem;               // overlay on stage bufs, post-pass-1
    int*   scnt  = (int*)(smem + OFF_SC);
    float* tq    = (float*)(smem + OFF_TQ);
    float* skeys = (float*)smem;               // pass-3 overlay
    int*   kn    = (int*)(smem + OFF_KN);
    float* pl    = (float*)smem;               // epilogue overlays
    float* hh    = (float*)(smem + OFF_HH);

    const int tid  = threadIdx.x;
    const int lane = tid & 63;
    const int w    = tid >> 6;                 // 0..15
    const int g    = w >> 2;                   // scan group 0..3 (tile & 3 == g)
    const int lw   = w & 3;                    // wave within group
    const int col  = lane & 15;                // candidate column / A-frag row
    const int quad = lane >> 4;
    const float INF = __builtin_inff();

    const int qb0 = blockIdx.x * QPB;
    const int b   = qb0 >> 13;
    const int qbl = qb0 & (NPTS - 1);
    const int S   = blockIdx.x & 31;           // tile-order stagger
    const float* xb  = x   + (size_t)(b << 13) * CCH;
    const float* sqb = sqg + (b << 13);
    const char*  xhb = (const char*)xh + (size_t)b * NTIL * (TILEC * CCH * 2);

    // ---- A-fragment from fp16 workspace: A[m=col][k=quad*8+j], queries lw*16+col
    half8 qh;
    {
        int p = qb0 + lw * 16 + col;
        qh = *(const half8*)((const char*)xh
              + (size_t)(p >> 6) * 4096 + ((p >> 4) & 3) * 1024
              + quad * 256 + (p & 15) * 16);
    }

    auto tileof = [&](int I) { return ((((I + S) & 31) << 2) | g); };
    auto bufat  = [&](int I) { return smem + (((g << 1) | (I & 1)) * 4352); };

    // async stage of super-iter I's tile for this group: 4KB fp16 + 256B sq
    auto stage = [&](int I) {
        char* sb = bufat(I);
        int tile = tileof(I);
        const char* src = xhb + (size_t)tile * 4096;
        gload_lds16(src + lw * 1024 + lane * 16, sb + lw * 1024);  // lds = base + lane*16
        if (lw == 0)
            gload_lds4(sqb + tile * TILEC + lane, sb + OFF_SQ);    // lds = base + lane*4
    };

    // ================= PASS 1: branch-free per-lane top-2 per query ==========
    float m1[4] = {INF, INF, INF, INF};
    float m2[4] = {INF, INF, INF, INF};

    stage(0);
    __syncthreads();
    #pragma unroll 1
    for (int I = 0; I < 32; ++I) {
        if (I + 1 < 32) stage(I + 1);
        const char*  cb = bufat(I);
        const float* sv = (const float*)(cb + OFF_SQ);
        #pragma unroll
        for (int st = 0; st < 4; ++st) {
            half8 bh = *(const half8*)(cb + st * 1024 + lane * 16);   // conflict-free
            float sc = sv[st * 16 + col];
            float4v acc = __builtin_amdgcn_mfma_f32_16x16x32_f16(
                qh, bh, (float4v){0.f, 0.f, 0.f, 0.f}, 0, 0, 0);
            #pragma unroll
            for (int j = 0; j < 4; ++j) {
                float key = fmaf(-2.f, acc[j], sc);
                float o1  = m1[j];
                m1[j] = fminf(key, o1);
                // 2nd-smallest of {key, o1, m2} == min(m2, max(key, o1)) given o1<=m2
                m2[j] = __builtin_amdgcn_fmed3f(key, o1, m2[j]);
            }
        }
        __syncthreads();
    }

    // ---- per-query threshold: 16th smallest of the 128-value union ----
    // Rank-based (exact, lex tie-break): rank(i) = #{j : v_j < v_i or (==, j<i)}.
    // Ranks are a permutation of 0..127 -> exactly one rank-15 writer per query.
    #pragma unroll
    for (int j = 0; j < 4; ++j) {
        int qq = lw * 16 + quad * 4 + j;
        t32[qq * T32STR + g * 32 + col * 2 + 0] = m1[j];
        t32[qq * T32STR + g * 32 + col * 2 + 1] = m2[j];
    }
    __syncthreads();
    {
        int q  = tid & 63;                     // query
        int wt = tid >> 6;                     // worker 0..15, items wt*8..wt*8+7
        float v[8]; int r[8];
        #pragma unroll
        for (int u = 0; u < 8; ++u) { v[u] = t32[q * T32STR + wt * 8 + u]; r[u] = 0; }
        #pragma unroll 8
        for (int jj = 0; jj < 128; ++jj) {
            float vj = t32[q * T32STR + jj];   // odd stride -> 2-way max, no conflicts
            #pragma unroll
            for (int u = 0; u < 8; ++u)
                r[u] += (int)(vj < v[u]) | ((int)(vj == v[u]) & (int)(jj < wt * 8 + u));
        }
        #pragma unroll
        for (int u = 0; u < 8; ++u)
            if (r[u] == KNN - 1) tq[q] = v[u];
        if (tid < QPB) scnt[tid] = 0;
    }
    __syncthreads();
    float T2[4];
    #pragma unroll
    for (int j = 0; j < 4; ++j) T2[j] = tq[lw * 16 + quad * 4 + j] + MARGIN;

    // ================= PASS 2: rescan, atomic survivor append ==========
    stage(0);
    __syncthreads();
    #pragma unroll 1
    for (int I = 0; I < 32; ++I) {
        if (I + 1 < 32) stage(I + 1);
        const char*  cb = bufat(I);
        const float* sv = (const float*)(cb + OFF_SQ);
        int tbase = tileof(I) * TILEC;
        #pragma unroll
        for (int st = 0; st < 4; ++st) {
            half8 bh = *(const half8*)(cb + st * 1024 + lane * 16);
            float sc = sv[st * 16 + col];
            float4v acc = __builtin_amdgcn_mfma_f32_16x16x32_f16(
                qh, bh, (float4v){0.f, 0.f, 0.f, 0.f}, 0, 0, 0);
            #pragma unroll
            for (int j = 0; j < 4; ++j) {
                float key = fmaf(-2.f, acc[j], sc);
                if (key < T2[j]) {
                    int qq = lw * 16 + quad * 4 + j;
                    int slot = atomicAdd(&scnt[qq], 1);
                    if (slot < SCAP)
                        slist[qq * SCAP + slot] = tbase + st * 16 + col;
                }
            }
        }
        __syncthreads();
    }

    // ================= PASS 3: exact fp32 re-check of survivors ==========
    // unroll 2 keeps the live set ~20 regs (no spill at the 64-VGPR budget)
    {
        int qq = tid & 63, sb16 = tid >> 6;    // 16 workers per query
        int n = scnt[qq]; if (n > SCAP) n = SCAP;
        const float4* xi4 = (const float4*)(xb + (size_t)(qbl + qq) * CCH);
        for (int s = sb16; s < n; s += 16) {
            int jdx = slist[qq * SCAP + s];
            const float4* xj = (const float4*)(xb + (size_t)jdx * CCH);
            float a0 = 0.f, a1 = 0.f, a2 = 0.f, a3 = 0.f;
            #pragma unroll 2
            for (int k = 0; k < 8; ++k) {
                float4 cv = xj[k], qv = xi4[k];
                a0 = fmaf(cv.x, qv.x, a0); a1 = fmaf(cv.y, qv.y, a1);
                a2 = fmaf(cv.z, qv.z, a2); a3 = fmaf(cv.w, qv.w, a3);
            }
            float dot = (a0 + a1) + (a2 + a3);
            skeys[qq * SCAP + s] = fmaf(-2.f, dot, sqb[jdx]);
        }
    }
    __syncthreads();
    // ---- exact top-16 set via rank (lex on (key, idx)); kn order = rank, set exact.
    // n >= 16 guaranteed (threshold >= true 16th + MARGIN covers fp16 error).
    {
        int q  = tid & 63;
        int wt = tid >> 6;
        int n = scnt[q]; if (n > SCAP) n = SCAP;
        for (int s = wt; s < n; s += 16) {
            float k = skeys[q * SCAP + s];
            int   i = slist[q * SCAP + s];
            int rank = 0;
            #pragma unroll 4
            for (int jj = 0; jj < n; ++jj) {
                float kj = skeys[q * SCAP + jj];   // stride 57 -> conflict-free
                int   ij = slist[q * SCAP + jj];
                rank += (int)(kj < k) | ((int)(kj == k) & (int)(ij < i));
            }
            if (rank < KNN) kn[q * KNN + rank] = i;
        }
    }
    __syncthreads();

    // ================= epilogue: gather + max-pool + MLP ==========
    {
        int q = tid >> 4, part = tid & 15;     // 16 threads/query, one float2 each
        float2 m0 = make_float2(-INF, -INF);
        #pragma unroll 4
        for (int k = 0; k < KNN; ++k) {
            int j = kn[q * KNN + k];
            float2 v = *(const float2*)(xb + (size_t)j * CCH + part * 2);
            m0.x = fmaxf(m0.x, v.x); m0.y = fmaxf(m0.y, v.y);
        }
        float* d = pl + q * 33 + part * 2;
        d[0] = m0.x; d[1] = m0.y;
    }
    __syncthreads();
    {
        int l = tid & 63, qg2 = tid >> 6;      // 16 query-slices
        #pragma unroll 1
        for (int qq = qg2; qq < QPB; qq += 16) {
            float acc = bl[l];
            #pragma unroll 8
            for (int c = 0; c < CCH; ++c)
                acc = fmaf(pl[qq * 33 + c], Wl[c * LDIM + l], acc);
            hh[qq * 65 + l] = acc;
        }
    }
    __syncthreads();
    {
        int o = tid & 127, qh2 = tid >> 7;     // 8 query-slices
        #pragma unroll 1
        for (int qq = qh2; qq < QPB; qq += 8) {
            float acc = bc[o];
            #pragma unroll 8
            for (int l = 0; l < LDIM; ++l)
                acc = fmaf(hh[qq * 65 + l], Wc[l * ODIM + o], acc);
            out[(size_t)(qb0 + qq) * ODIM + o] = fmaxf(acc, 0.f);
        }
    }
}

extern "C" void kernel_launch(void* const* d_in, const int* in_sizes, int n_in,
                              void* d_out, int out_size, void* d_ws, size_t ws_size,
                              hipStream_t stream) {
    const float* x  = (const float*)d_in[0];
    const float* Wl = (const float*)d_in[1];
    const float* bl = (const float*)d_in[2];
    const float* Wc = (const float*)d_in[3];
    const float* bc = (const float*)d_in[4];
    float* out = (float*)d_out;
    float*    sqf = (float*)d_ws;                       // 32768 fp32 = 128 KB
    _Float16* xh  = (_Float16*)((char*)d_ws + 131072);  // 32768 x 32 fp16 = 2 MB, frag-order
    (void)in_sizes; (void)n_in; (void)out_size; (void)ws_size;

    hipLaunchKernelGGL(prep_kernel, dim3((4 * NPTS) / 256), dim3(256), 0, stream, x, sqf, xh);
    hipLaunchKernelGGL(graph_layer_kernel, dim3(NBLK), dim3(1024), 0, stream,
                       x, sqf, xh, Wl, bl, Wc, bc, out);
}

// Round 8
// 283.564 us; speedup vs baseline: 1.1683x; 1.1683x over previous
//
#include <hip/hip_runtime.h>

#define NPTS   8192
#define CCH    32
#define LDIM   64
#define ODIM   128
#define KNN    16
#define QPB    64                  // queries per block = 4 waves x 16
#define TILEC  64                  // candidates per register tile
#define NTIL   128                 // tiles per batch
#define TREC   4352                // tile record: 4096B fp16 fragments + 256B sq[col][st]
#define NBLK   ((4 * NPTS) / QPB)  // 512 blocks
#define SCAP   57                  // survivor capacity (16-col top-2 threshold: worst ~40)
#define MARGIN 0.75f               // >= 2*eps bound for fp16 distance error

typedef _Float16 half8   __attribute__((ext_vector_type(8)));
typedef float    float4v __attribute__((ext_vector_type(4)));

// BARRIER-FREE REGISTER SCAN (R7 post-mortem): every LDS-staged variant
// (R2-R7) pinned at 5-7.5% MfmaUtil because __syncthreads() per tile drains
// vmcnt(0) on the just-issued prefetch -> latency convoy; and total waves are
// capped at 2048 (= queries/16) = 2/SIMD, so TLP can't hide it. This version
// scans with NO LDS and NO barriers: each wave loads B-fragments directly
// global->VGPR (workspace is already in per-lane fragment order), 4-deep
// register pipeline; the compiler's counted vmcnt gives a 3-compute-phase
// load->use window > L2 latency. MFMA C is preloaded with sq[cand] and the
// A-fragment prescaled by -2 (both exact), so acc IS the key: inner loop is
// 2 VALU/cell. ~8 barriers total in the kernel (vs ~70).
//
// LDS map (no scan buffers):
//  slist @0 (64*57*4=14592) | skeys @14592 (14592) | scnt @29184 (256)
//  tq @29440 (256) | kn @29696 (4096) -> 33792 total
//  t32 overlay @14592 (64*33*4=8448; dead before skeys)
//  epilogue: pl @0 (8448) | hh @8448 (16640; ends 25088, kn alive @29696)
#define OFF_SK   14592
#define OFF_T32  14592
#define OFF_SCN  29184
#define OFF_TQ   29440
#define OFF_KN   29696
#define OFF_HH   8448
#define LDS_BYTES 33792

// Prologue: fp32 squared norms (same summation order -> identical bits) and
// fp16 candidates written ONCE per 64-cand tile record:
//   point p: tile=p>>6, st=(p>>4)&3, col=p&15; chan c=q*8+j ->
//   rec + st*1024 + q*256 + col*16 + j*2 ; sq at rec + 4096 + col*16 + st*4
// so a lane's B-fragment is one dwordx4 at rec + st*1024 + lane*16, and the
// 4 sq values for st=0..3 are one dwordx4 at rec + 4096 + col*16.
__global__ void prep_kernel(const float* __restrict__ x, float* __restrict__ sqg,
                            char* __restrict__ xh2) {
    int p = blockIdx.x * 256 + threadIdx.x;      // 0..32767
    const float4* src = (const float4*)(x + (size_t)p * CCH);
    float4 f[8];
    #pragma unroll
    for (int k = 0; k < 8; ++k) f[k] = src[k];
    float s = 0.f;
    #pragma unroll
    for (int k = 0; k < 8; ++k)
        s += f[k].x * f[k].x + f[k].y * f[k].y + f[k].z * f[k].z + f[k].w * f[k].w;
    sqg[p] = s;
    int b = p >> 13, pp = p & (NPTS - 1);
    char* rec = xh2 + (size_t)b * NTIL * TREC + (size_t)(pp >> 6) * TREC;
    int st = (pp >> 4) & 3, col = pp & 15;
    char* fd = rec + st * 1024 + col * 16;
    #pragma unroll
    for (int q = 0; q < 4; ++q) {
        float4 a = f[2 * q], c = f[2 * q + 1];
        half8 h;
        h[0] = (_Float16)a.x; h[1] = (_Float16)a.y; h[2] = (_Float16)a.z; h[3] = (_Float16)a.w;
        h[4] = (_Float16)c.x; h[5] = (_Float16)c.y; h[6] = (_Float16)c.z; h[7] = (_Float16)c.w;
        *(half8*)(fd + q * 256) = h;
    }
    *(float*)(rec + 4096 + col * 16 + st * 4) = s;
}

__global__ __launch_bounds__(256, 2)
void graph_layer_kernel(const float* __restrict__ x,
                        const float* __restrict__ sqg,
                        const char* __restrict__ xh2,
                        const float* __restrict__ Wl,
                        const float* __restrict__ bl,
                        const float* __restrict__ Wc,
                        const float* __restrict__ bc,
                        float* __restrict__ out)
{
    __shared__ __align__(16) char smem[LDS_BYTES];
    int*   slist = (int*)smem;
    float* skeys = (float*)(smem + OFF_SK);
    float* t32   = (float*)(smem + OFF_T32);
    int*   scnt  = (int*)(smem + OFF_SCN);
    float* tq    = (float*)(smem + OFF_TQ);
    int*   kn    = (int*)(smem + OFF_KN);
    float* pl    = (float*)smem;               // epilogue overlays
    float* hh    = (float*)(smem + OFF_HH);

    const int tid  = threadIdx.x;
    const int lane = tid & 63;
    const int w    = tid >> 6;                 // 0..3
    const int col  = lane & 15;                // candidate column / D col
    const int quad = lane >> 4;
    const float INF = __builtin_inff();

    const int qb0 = blockIdx.x * QPB;
    const int b   = qb0 >> 13;
    const int qbl = qb0 & (NPTS - 1);
    const int S   = blockIdx.x & (NTIL - 1);   // tile-order stagger across blocks
    const float* xb  = x   + (size_t)(b << 13) * CCH;
    const float* sqb = sqg + (b << 13);
    const char*  xhb = xh2 + (size_t)b * NTIL * TREC;

    // ---- A-fragment, prescaled by -2 (exact in fp16): MFMA out = sq[c] - 2 q.c
    half8 qh;
    {
        int pp = qbl + w * 16 + col;
        qh = *(const half8*)(xhb + (size_t)(pp >> 6) * TREC
                             + ((pp >> 4) & 3) * 1024 + quad * 256 + col * 16);
        #pragma unroll
        for (int i = 0; i < 8; ++i) qh[i] = qh[i] * (_Float16)-2.0f;
    }

    const char* lbase = xhb + (size_t)lane * 16;        // per-lane fragment base
    const char* sbase = xhb + 4096 + (size_t)col * 16;  // per-lane sq base

    half8 f0[4], f1[4], f2[4], f3[4];
    float4v s0v, s1v, s2v, s3v;

#define LDSET(F, SV, T) { \
        int _t = ((T) + S) & (NTIL - 1); \
        const char* _r = lbase + (size_t)_t * TREC; \
        F[0] = *(const half8*)(_r); \
        F[1] = *(const half8*)(_r + 1024); \
        F[2] = *(const half8*)(_r + 2048); \
        F[3] = *(const half8*)(_r + 3072); \
        SV = *(const float4v*)(sbase + (size_t)_t * TREC); \
    }

    // ================= PASS 1: branch-free per-lane top-2 per query ==========
    float m1[4] = {INF, INF, INF, INF};
    float m2[4] = {INF, INF, INF, INF};

#define PASS1(F, SV) { \
        _Pragma("unroll") \
        for (int st = 0; st < 4; ++st) { \
            float sc = SV[st]; \
            float4v acc = __builtin_amdgcn_mfma_f32_16x16x32_f16( \
                qh, F[st], (float4v){sc, sc, sc, sc}, 0, 0, 0); \
            _Pragma("unroll") \
            for (int j = 0; j < 4; ++j) { \
                float key = acc[j]; \
                float o1  = m1[j]; \
                m1[j] = fminf(key, o1); \
                m2[j] = __builtin_amdgcn_fmed3f(key, o1, m2[j]); \
            } \
        } \
    }

    LDSET(f0, s0v, 0) LDSET(f1, s1v, 1) LDSET(f2, s2v, 2) LDSET(f3, s3v, 3)
    #pragma unroll 1
    for (int T = 0; T < NTIL; T += 4) {
        PASS1(f0, s0v) LDSET(f0, s0v, T + 4)   // tail loads wrap (&127), unused: harmless
        PASS1(f1, s1v) LDSET(f1, s1v, T + 5)
        PASS1(f2, s2v) LDSET(f2, s2v, T + 6)
        PASS1(f3, s3v) LDSET(f3, s3v, T + 7)
    }

    // ---- per-query threshold: 16th smallest of 16-col x top-2 = 32 values ----
    // (original partition scheme -> SCAP analysis: worst ~40 survivors <= 57)
    #pragma unroll
    for (int j = 0; j < 4; ++j) {
        int qq = w * 16 + quad * 4 + j;
        t32[qq * 33 + col * 2 + 0] = m1[j];
        t32[qq * 33 + col * 2 + 1] = m2[j];
    }
    __syncthreads();
    {
        int q = tid & 63, wt = tid >> 6;       // 4 workers x 8 items
        float v[8]; int r[8];
        #pragma unroll
        for (int u = 0; u < 8; ++u) { v[u] = t32[q * 33 + wt * 8 + u]; r[u] = 0; }
        #pragma unroll 8
        for (int jj = 0; jj < 32; ++jj) {
            float vj = t32[q * 33 + jj];
            #pragma unroll
            for (int u = 0; u < 8; ++u)
                r[u] += (int)(vj < v[u]) | ((int)(vj == v[u]) & (int)(jj < wt * 8 + u));
        }
        #pragma unroll
        for (int u = 0; u < 8; ++u)
            if (r[u] == KNN - 1) tq[q] = v[u];
        if (tid < QPB) scnt[tid] = 0;
    }
    __syncthreads();
    float T2[4];
    #pragma unroll
    for (int j = 0; j < 4; ++j) T2[j] = tq[w * 16 + quad * 4 + j] + MARGIN;

    // ================= PASS 2: rescan, atomic survivor append ==========
#define PASS2(F, SV, T) { \
        int _tb = (((T) + S) & (NTIL - 1)) * TILEC; \
        _Pragma("unroll") \
        for (int st = 0; st < 4; ++st) { \
            float sc = SV[st]; \
            float4v acc = __builtin_amdgcn_mfma_f32_16x16x32_f16( \
                qh, F[st], (float4v){sc, sc, sc, sc}, 0, 0, 0); \
            _Pragma("unroll") \
            for (int j = 0; j < 4; ++j) { \
                float key = acc[j]; \
                if (key < T2[j]) { \
                    int qq = w * 16 + quad * 4 + j; \
                    int slot = atomicAdd(&scnt[qq], 1); \
                    if (slot < SCAP) slist[qq * SCAP + slot] = _tb + st * 16 + col; \
                } \
            } \
        } \
    }

    LDSET(f0, s0v, 0) LDSET(f1, s1v, 1) LDSET(f2, s2v, 2) LDSET(f3, s3v, 3)
    #pragma unroll 1
    for (int T = 0; T < NTIL; T += 4) {
        PASS2(f0, s0v, T)     LDSET(f0, s0v, T + 4)
        PASS2(f1, s1v, T + 1) LDSET(f1, s1v, T + 5)
        PASS2(f2, s2v, T + 2) LDSET(f2, s2v, T + 6)
        PASS2(f3, s3v, T + 3) LDSET(f3, s3v, T + 7)
    }
    __syncthreads();

    // ================= PASS 3: exact fp32 re-check of survivors ==========
    {
        int qq = tid & 63, sb4 = tid >> 6;     // 4 workers per query
        int n = scnt[qq]; if (n > SCAP) n = SCAP;
        const float4* xi4 = (const float4*)(xb + (size_t)(qbl + qq) * CCH);
        for (int s = sb4; s < n; s += 4) {
            int jdx = slist[qq * SCAP + s];
            const float4* xj = (const float4*)(xb + (size_t)jdx * CCH);
            float a0 = 0.f, a1 = 0.f, a2 = 0.f, a3 = 0.f;
            #pragma unroll 2
            for (int k = 0; k < 8; ++k) {
                float4 cv = xj[k], qv = xi4[k];
                a0 = fmaf(cv.x, qv.x, a0); a1 = fmaf(cv.y, qv.y, a1);
                a2 = fmaf(cv.z, qv.z, a2); a3 = fmaf(cv.w, qv.w, a3);
            }
            float dot = (a0 + a1) + (a2 + a3);
            skeys[qq * SCAP + s] = fmaf(-2.f, dot, sqb[jdx]);
        }
    }
    __syncthreads();
    // ---- exact top-16 set via rank (lex on (key, idx)); kn order = rank.
    {
        int q = tid & 63, wt = tid >> 6;
        int n = scnt[q]; if (n > SCAP) n = SCAP;
        for (int s = wt; s < n; s += 4) {
            float k = skeys[q * SCAP + s];
            int   i = slist[q * SCAP + s];
            int rank = 0;
            #pragma unroll 4
            for (int jj = 0; jj < n; ++jj) {
                float kj = skeys[q * SCAP + jj];   // stride 57 -> conflict-free
                int   ij = slist[q * SCAP + jj];
                rank += (int)(kj < k) | ((int)(kj == k) & (int)(ij < i));
            }
            if (rank < KNN) kn[q * KNN + rank] = i;
        }
    }
    __syncthreads();

    // ================= epilogue: gather + max-pool + MLP ==========
    {
        int q = tid >> 2, part = tid & 3;      // 4 threads/query, two float4 each
        float4 m0 = make_float4(-INF, -INF, -INF, -INF);
        float4 mm1 = m0;
        #pragma unroll 4
        for (int k = 0; k < KNN; ++k) {
            int j = kn[q * KNN + k];
            const float4* r = (const float4*)(xb + (size_t)j * CCH + part * 8);
            float4 v0 = r[0], v1 = r[1];
            m0.x = fmaxf(m0.x, v0.x); m0.y = fmaxf(m0.y, v0.y);
            m0.z = fmaxf(m0.z, v0.z); m0.w = fmaxf(m0.w, v0.w);
            mm1.x = fmaxf(mm1.x, v1.x); mm1.y = fmaxf(mm1.y, v1.y);
            mm1.z = fmaxf(mm1.z, v1.z); mm1.w = fmaxf(mm1.w, v1.w);
        }
        float* d = pl + q * 33 + part * 8;
        d[0] = m0.x; d[1] = m0.y; d[2] = m0.z; d[3] = m0.w;
        d[4] = mm1.x; d[5] = mm1.y; d[6] = mm1.z; d[7] = mm1.w;
    }
    __syncthreads();
    {
        int l = tid & 63, qg2 = tid >> 6;      // 4 query-slices
        #pragma unroll 1
        for (int qq = qg2; qq < QPB; qq += 4) {
            float acc = bl[l];
            #pragma unroll 8
            for (int c = 0; c < CCH; ++c)
                acc = fmaf(pl[qq * 33 + c], Wl[c * LDIM + l], acc);
            hh[qq * 65 + l] = acc;
        }
    }
    __syncthreads();
    {
        int o = tid & 127, qh2 = tid >> 7;     // 2 query-slices
        #pragma unroll 1
        for (int qq = qh2; qq < QPB; qq += 2) {
            float acc = bc[o];
            #pragma unroll 8
            for (int l = 0; l < LDIM; ++l)
                acc = fmaf(hh[qq * 65 + l], Wc[l * ODIM + o], acc);
            out[(size_t)(qb0 + qq) * ODIM + o] = fmaxf(acc, 0.f);
        }
    }
}

extern "C" void kernel_launch(void* const* d_in, const int* in_sizes, int n_in,
                              void* d_out, int out_size, void* d_ws, size_t ws_size,
                              hipStream_t stream) {
    const float* x  = (const float*)d_in[0];
    const float* Wl = (const float*)d_in[1];
    const float* bl = (const float*)d_in[2];
    const float* Wc = (const float*)d_in[3];
    const float* bc = (const float*)d_in[4];
    float* out = (float*)d_out;
    float* sqf = (float*)d_ws;                          // 32768 fp32 = 128 KB
    char*  xh2 = (char*)d_ws + 131072;                  // 4 batches x 128 tiles x 4352 B = 2.125 MB
    (void)in_sizes; (void)n_in; (void)out_size; (void)ws_size;

    hipLaunchKernelGGL(prep_kernel, dim3((4 * NPTS) / 256), dim3(256), 0, stream, x, sqf, xh2);
    hipLaunchKernelGGL(graph_layer_kernel, dim3(NBLK), dim3(256), 0, stream,
                       x, sqf, xh2, Wl, bl, Wc, bc, out);
}